// Round 3
// baseline (1074.712 us; speedup 1.0000x reference)
//
#include <hip/hip_runtime.h>
#include <hip/hip_bf16.h>

#define BATCH 8
#define SEQ   2048
#define DIM   128

// reference: A = (Q.K)/sqrt(128), z = A/2  ->  z = S * 1/(2*sqrt(128))
#define INV_2SQRTD 0.04419417382415922f

// ---------------------------------------------------------------------------
// Projection: Out[row,d] = sum_e X[row,e] * W[d,e] + bias[d]   (f32 in/out)
// grid = B*N, block = 128 (thread d -> one output column)
// ---------------------------------------------------------------------------
__global__ void project_f32(const float* __restrict__ X,
                            const float* __restrict__ W,
                            const float* __restrict__ bias,
                            float* __restrict__ Out) {
    const int row = blockIdx.x;
    const int d   = threadIdx.x;
    __shared__ float xs[DIM];
    xs[d] = X[(size_t)row * DIM + d];
    __syncthreads();

    const float4* wp = reinterpret_cast<const float4*>(W + (size_t)d * DIM);
    float s = bias[d];
#pragma unroll
    for (int c = 0; c < 32; ++c) {
        float4 w = wp[c];
        s += w.x * xs[c * 4 + 0];
        s += w.y * xs[c * 4 + 1];
        s += w.z * xs[c * 4 + 2];
        s += w.w * xs[c * 4 + 3];
    }
    Out[(size_t)row * DIM + d] = s;
}

__global__ void project_bf16(const float* __restrict__ X,
                             const float* __restrict__ W,
                             const float* __restrict__ bias,
                             __hip_bfloat16* __restrict__ Out) {
    const int row = blockIdx.x;
    const int d   = threadIdx.x;
    __shared__ float xs[DIM];
    xs[d] = X[(size_t)row * DIM + d];
    __syncthreads();

    const float4* wp = reinterpret_cast<const float4*>(W + (size_t)d * DIM);
    float s = bias[d];
#pragma unroll
    for (int c = 0; c < 32; ++c) {
        float4 w = wp[c];
        s += w.x * xs[c * 4 + 0];
        s += w.y * xs[c * 4 + 1];
        s += w.z * xs[c * 4 + 2];
        s += w.w * xs[c * 4 + 3];
    }
    Out[(size_t)row * DIM + d] = __float2bfloat16(s);
}

// ---------------------------------------------------------------------------
// Transpose K[b][j][d] (bf16) -> Kt[b][d][j] (bf16).  64x64 LDS tiles.
// grid = (SEQ/64, DIM/64, B), block = 256
// ---------------------------------------------------------------------------
__global__ void transpose_k(const __hip_bfloat16* __restrict__ Kin,
                            __hip_bfloat16* __restrict__ Kt) {
    const int j0 = blockIdx.x * 64;
    const int d0 = blockIdx.y * 64;
    const int b  = blockIdx.z;
    __shared__ unsigned short tile[64][66];   // +2 pad: odd dword stride

    const int tid = threadIdx.x;
    const int tx4 = (tid & 15) * 4;
    const int r0  = tid >> 4;                 // 0..15

    const unsigned short* inb =
        reinterpret_cast<const unsigned short*>(Kin) + (size_t)b * SEQ * DIM;
#pragma unroll
    for (int k = 0; k < 4; ++k) {
        const int r = r0 + k * 16;
        uint2 v = *reinterpret_cast<const uint2*>(
            inb + (size_t)(j0 + r) * DIM + d0 + tx4);
        tile[r][tx4 + 0] = (unsigned short)(v.x & 0xffffu);
        tile[r][tx4 + 1] = (unsigned short)(v.x >> 16);
        tile[r][tx4 + 2] = (unsigned short)(v.y & 0xffffu);
        tile[r][tx4 + 3] = (unsigned short)(v.y >> 16);
    }
    __syncthreads();

    unsigned short* outb =
        reinterpret_cast<unsigned short*>(Kt) + (size_t)b * DIM * SEQ;
#pragma unroll
    for (int k = 0; k < 4; ++k) {
        const int dd = r0 + k * 16;
        unsigned int w0 = (unsigned int)tile[tx4 + 0][dd] |
                          ((unsigned int)tile[tx4 + 1][dd] << 16);
        unsigned int w1 = (unsigned int)tile[tx4 + 2][dd] |
                          ((unsigned int)tile[tx4 + 3][dd] << 16);
        uint2 o; o.x = w0; o.y = w1;
        *reinterpret_cast<uint2*>(
            outb + (size_t)(d0 + dd) * SEQ + j0 + tx4) = o;
    }
}

// ---------------------------------------------------------------------------
// Scores + exact 1.5-entmax. One wave per 4 query rows; lane t owns keys
// j = g*512 + t*8 + i (g<4, i<8) for each row. K reads are coalesced
// (Kt is [b][d][j]); each K chunk is reused by 4 rows (register blocking).
// tau* solved by bisection on f(tau)=sum max(z-tau,0)^2 (dec., root in [-1,0]).
// Output is FLOAT32 (reference output dtype).
// ---------------------------------------------------------------------------
__global__ void attn_entmax_kernel(const float* __restrict__ Q,
                                   const __hip_bfloat16* __restrict__ Kt,
                                   float* __restrict__ out) {
    const int row0 = blockIdx.x * 4;          // 4 rows, same batch (2048%4==0)
    const int b    = row0 >> 11;
    const int t    = threadIdx.x;             // 0..63

    __shared__ float qs[DIM * 4];             // qs[d*4 + p]
#pragma unroll
    for (int m = 0; m < 8; ++m) {
        const int idx = m * 64 + t;           // = d*4 + p
        const int p = idx & 3;
        const int d = idx >> 2;
        qs[idx] = Q[(size_t)(row0 + p) * DIM + d];
    }
    __syncthreads();

    const __hip_bfloat16* Kb = Kt + (size_t)b * DIM * SEQ;

    float sc[4][32];
#pragma unroll
    for (int p = 0; p < 4; ++p)
#pragma unroll
        for (int r = 0; r < 32; ++r) sc[p][r] = 0.0f;

    for (int d = 0; d < DIM; ++d) {
        const float4 qv = *reinterpret_cast<const float4*>(qs + d * 4);
        const float qp[4] = {qv.x, qv.y, qv.z, qv.w};
        const __hip_bfloat16* kdp = Kb + (size_t)d * SEQ + t * 8;
#pragma unroll
        for (int g = 0; g < 4; ++g) {
            union { float4 v; unsigned int w[4]; } kr;
            kr.v = *reinterpret_cast<const float4*>(kdp + g * 512);
            float kf[8];
#pragma unroll
            for (int w = 0; w < 4; ++w) {
                kf[2 * w]     = __uint_as_float(kr.w[w] << 16);
                kf[2 * w + 1] = __uint_as_float(kr.w[w] & 0xffff0000u);
            }
#pragma unroll
            for (int p = 0; p < 4; ++p) {
                const float q = qp[p];
#pragma unroll
                for (int u = 0; u < 8; ++u)
                    sc[p][g * 8 + u] = fmaf(q, kf[u], sc[p][g * 8 + u]);
            }
        }
    }

#pragma unroll
    for (int p = 0; p < 4; ++p) {
        // row max across all 2048 entries
        float m = sc[p][0];
#pragma unroll
        for (int r = 1; r < 32; ++r) m = fmaxf(m, sc[p][r]);
#pragma unroll
        for (int off = 32; off >= 1; off >>= 1) m = fmaxf(m, __shfl_xor(m, off));

        // z = (S - max)/(2*sqrt(D)) ; z <= 0, z_max = 0
#pragma unroll
        for (int r = 0; r < 32; ++r) sc[p][r] = (sc[p][r] - m) * INV_2SQRTD;

        // bisection: f(-1) >= 1 (term at z_max contributes 1), f(0) = 0
        float lo = -1.0f, hi = 0.0f;
        for (int it = 0; it < 26; ++it) {
            const float tau = 0.5f * (lo + hi);
            float fs = 0.0f;
#pragma unroll
            for (int r = 0; r < 32; ++r) {
                float dz = fmaxf(sc[p][r] - tau, 0.0f);
                fs = fmaf(dz, dz, fs);
            }
#pragma unroll
            for (int off = 32; off >= 1; off >>= 1) fs += __shfl_xor(fs, off);
            if (fs >= 1.0f) lo = tau; else hi = tau;
        }
        const float tau = 0.5f * (lo + hi);

        // p_j = max(z_j - tau, 0)^2 -> f32, two float4 (32B) per lane per group
        float* orow = out + (size_t)(row0 + p) * SEQ;
#pragma unroll
        for (int g = 0; g < 4; ++g) {
            float pv[8];
#pragma unroll
            for (int u = 0; u < 8; ++u) {
                float dz = fmaxf(sc[p][g * 8 + u] - tau, 0.0f);
                pv[u] = dz * dz;
            }
            float4 lov = make_float4(pv[0], pv[1], pv[2], pv[3]);
            float4 hiv = make_float4(pv[4], pv[5], pv[6], pv[7]);
            *reinterpret_cast<float4*>(orow + g * 512 + t * 8)     = lov;
            *reinterpret_cast<float4*>(orow + g * 512 + t * 8 + 4) = hiv;
        }
    }
}

// ---------------------------------------------------------------------------
extern "C" void kernel_launch(void* const* d_in, const int* in_sizes, int n_in,
                              void* d_out, int out_size, void* d_ws, size_t ws_size,
                              hipStream_t stream) {
    const float* x_c = (const float*)d_in[0];
    const float* x_n = (const float*)d_in[1];
    const float* Wq  = (const float*)d_in[2];
    const float* bq  = (const float*)d_in[3];
    const float* Wk  = (const float*)d_in[4];
    const float* bk  = (const float*)d_in[5];
    float* out = (float*)d_out;

    char* ws = (char*)d_ws;
    float*          Qf   = (float*)ws;                                       // 8 MB
    __hip_bfloat16* Krow = (__hip_bfloat16*)(ws + (size_t)8  * 1024 * 1024); // 4 MB
    __hip_bfloat16* Kt   = (__hip_bfloat16*)(ws + (size_t)12 * 1024 * 1024); // 4 MB

    project_f32 <<<BATCH * SEQ, DIM, 0, stream>>>(x_c, Wq, bq, Qf);
    project_bf16<<<BATCH * SEQ, DIM, 0, stream>>>(x_n, Wk, bk, Krow);
    transpose_k <<<dim3(SEQ / 64, DIM / 64, BATCH), 256, 0, stream>>>(Krow, Kt);
    attn_entmax_kernel<<<BATCH * SEQ / 4, 64, 0, stream>>>(Qf, Kt, out);
}

// Round 4
// 343.274 us; speedup vs baseline: 3.1308x; 3.1308x over previous
//
#include <hip/hip_runtime.h>
#include <hip/hip_bf16.h>

#define BATCH 8
#define SEQ   2048
#define DIM   128

// reference: A = (Q.K)/sqrt(128), z = A/2  ->  z = S * 1/(2*sqrt(128))
#define INV_2SQRTD 0.04419417382415922f

// ---------------------------------------------------------------------------
// Projection: Out[row,d] = sum_e X[row,e] * W[d,e] + bias[d]   (f32 in/out)
// 8 rows per block so W (64 KB) is fetched once per 8 rows, not per row.
// grid = B*N/8, block = 128 (thread d -> one output column, 8 rows)
// ---------------------------------------------------------------------------
__global__ void __launch_bounds__(128)
project_f32(const float* __restrict__ X,
            const float* __restrict__ W,
            const float* __restrict__ bias,
            float* __restrict__ Out) {
    const int row0 = blockIdx.x * 8;
    const int d    = threadIdx.x;
    __shared__ float xs[8][DIM];
#pragma unroll
    for (int r = 0; r < 8; ++r) xs[r][d] = X[(size_t)(row0 + r) * DIM + d];
    __syncthreads();

    const float4* wp = reinterpret_cast<const float4*>(W + (size_t)d * DIM);
    const float bv = bias[d];
    float s[8];
#pragma unroll
    for (int r = 0; r < 8; ++r) s[r] = bv;
#pragma unroll
    for (int c = 0; c < 32; ++c) {
        float4 w = wp[c];
#pragma unroll
        for (int r = 0; r < 8; ++r) {
            float4 xv = *reinterpret_cast<const float4*>(&xs[r][c * 4]);
            s[r] = fmaf(w.x, xv.x, s[r]);
            s[r] = fmaf(w.y, xv.y, s[r]);
            s[r] = fmaf(w.z, xv.z, s[r]);
            s[r] = fmaf(w.w, xv.w, s[r]);
        }
    }
#pragma unroll
    for (int r = 0; r < 8; ++r) Out[(size_t)(row0 + r) * DIM + d] = s[r];
}

__global__ void __launch_bounds__(128)
project_bf16(const float* __restrict__ X,
             const float* __restrict__ W,
             const float* __restrict__ bias,
             __hip_bfloat16* __restrict__ Out) {
    const int row0 = blockIdx.x * 8;
    const int d    = threadIdx.x;
    __shared__ float xs[8][DIM];
#pragma unroll
    for (int r = 0; r < 8; ++r) xs[r][d] = X[(size_t)(row0 + r) * DIM + d];
    __syncthreads();

    const float4* wp = reinterpret_cast<const float4*>(W + (size_t)d * DIM);
    const float bv = bias[d];
    float s[8];
#pragma unroll
    for (int r = 0; r < 8; ++r) s[r] = bv;
#pragma unroll
    for (int c = 0; c < 32; ++c) {
        float4 w = wp[c];
#pragma unroll
        for (int r = 0; r < 8; ++r) {
            float4 xv = *reinterpret_cast<const float4*>(&xs[r][c * 4]);
            s[r] = fmaf(w.x, xv.x, s[r]);
            s[r] = fmaf(w.y, xv.y, s[r]);
            s[r] = fmaf(w.z, xv.z, s[r]);
            s[r] = fmaf(w.w, xv.w, s[r]);
        }
    }
#pragma unroll
    for (int r = 0; r < 8; ++r)
        Out[(size_t)(row0 + r) * DIM + d] = __float2bfloat16(s[r]);
}

// ---------------------------------------------------------------------------
// Transpose K[b][j][d] (bf16) -> Kt[b][d][j] (bf16).  64x64 LDS tiles.
// grid = (SEQ/64, DIM/64, B), block = 256
// ---------------------------------------------------------------------------
__global__ void __launch_bounds__(256)
transpose_k(const __hip_bfloat16* __restrict__ Kin,
            __hip_bfloat16* __restrict__ Kt) {
    const int j0 = blockIdx.x * 64;
    const int d0 = blockIdx.y * 64;
    const int b  = blockIdx.z;
    __shared__ unsigned short tile[64][66];   // +2 pad: odd dword stride

    const int tid = threadIdx.x;
    const int tx4 = (tid & 15) * 4;
    const int r0  = tid >> 4;                 // 0..15

    const unsigned short* inb =
        reinterpret_cast<const unsigned short*>(Kin) + (size_t)b * SEQ * DIM;
#pragma unroll
    for (int k = 0; k < 4; ++k) {
        const int r = r0 + k * 16;
        uint2 v = *reinterpret_cast<const uint2*>(
            inb + (size_t)(j0 + r) * DIM + d0 + tx4);
        tile[r][tx4 + 0] = (unsigned short)(v.x & 0xffffu);
        tile[r][tx4 + 1] = (unsigned short)(v.x >> 16);
        tile[r][tx4 + 2] = (unsigned short)(v.y & 0xffffu);
        tile[r][tx4 + 3] = (unsigned short)(v.y >> 16);
    }
    __syncthreads();

    unsigned short* outb =
        reinterpret_cast<unsigned short*>(Kt) + (size_t)b * DIM * SEQ;
#pragma unroll
    for (int k = 0; k < 4; ++k) {
        const int dd = r0 + k * 16;
        unsigned int w0 = (unsigned int)tile[tx4 + 0][dd] |
                          ((unsigned int)tile[tx4 + 1][dd] << 16);
        unsigned int w1 = (unsigned int)tile[tx4 + 2][dd] |
                          ((unsigned int)tile[tx4 + 3][dd] << 16);
        uint2 o; o.x = w0; o.y = w1;
        *reinterpret_cast<uint2*>(
            outb + (size_t)(d0 + dd) * SEQ + j0 + tx4) = o;
    }
}

// ---------------------------------------------------------------------------
// Scores + exact 1.5-entmax. One wave per 4 query rows; lane t owns keys
// j = g*512 + t*8 + i (g<4, i<8) for each row. Kt is [b][d][j] so K reads
// are coalesced; each K chunk is reused by 4 rows (register blocking).
// __launch_bounds__(64): lift the default-1024-thread VGPR cap (64) so the
// sc[4][32] accumulators live in registers, not scratch (round-3: 2 GB of
// spill traffic, VALUBusy 22%).
// ---------------------------------------------------------------------------
__global__ void __launch_bounds__(64)
attn_entmax_kernel(const float* __restrict__ Q,
                   const __hip_bfloat16* __restrict__ Kt,
                   float* __restrict__ out) {
    const int row0 = blockIdx.x * 4;          // 4 rows, same batch (2048%4==0)
    const int b    = row0 >> 11;
    const int t    = threadIdx.x;             // 0..63

    __shared__ float qs[DIM * 4];             // qs[d*4 + p]
#pragma unroll
    for (int m = 0; m < 8; ++m) {
        const int idx = m * 64 + t;           // = d*4 + p
        const int p = idx & 3;
        const int d = idx >> 2;
        qs[idx] = Q[(size_t)(row0 + p) * DIM + d];
    }
    __syncthreads();

    const __hip_bfloat16* Kb = Kt + (size_t)b * DIM * SEQ;

    float sc[4][32];
#pragma unroll
    for (int p = 0; p < 4; ++p)
#pragma unroll
        for (int r = 0; r < 32; ++r) sc[p][r] = 0.0f;

    for (int d = 0; d < DIM; ++d) {
        const float4 qv = *reinterpret_cast<const float4*>(qs + d * 4);
        const float qp[4] = {qv.x, qv.y, qv.z, qv.w};
        const __hip_bfloat16* kdp = Kb + (size_t)d * SEQ + t * 8;
#pragma unroll
        for (int g = 0; g < 4; ++g) {
            union { float4 v; unsigned int w[4]; } kr;
            kr.v = *reinterpret_cast<const float4*>(kdp + g * 512);
            float kf[8];
#pragma unroll
            for (int w = 0; w < 4; ++w) {
                kf[2 * w]     = __uint_as_float(kr.w[w] << 16);
                kf[2 * w + 1] = __uint_as_float(kr.w[w] & 0xffff0000u);
            }
#pragma unroll
            for (int p = 0; p < 4; ++p) {
                const float q = qp[p];
#pragma unroll
                for (int u = 0; u < 8; ++u)
                    sc[p][g * 8 + u] = fmaf(q, kf[u], sc[p][g * 8 + u]);
            }
        }
    }

#pragma unroll
    for (int p = 0; p < 4; ++p) {
        // row max across all 2048 entries
        float m = sc[p][0];
#pragma unroll
        for (int r = 1; r < 32; ++r) m = fmaxf(m, sc[p][r]);
#pragma unroll
        for (int off = 32; off >= 1; off >>= 1) m = fmaxf(m, __shfl_xor(m, off));

        // z = (S - max)/(2*sqrt(D)) ; z <= 0, z_max = 0
#pragma unroll
        for (int r = 0; r < 32; ++r) sc[p][r] = (sc[p][r] - m) * INV_2SQRTD;

        // bisection: f(tau)=sum max(z-tau,0)^2 strictly decreasing on [-1,0];
        // f(-1) >= 1 (z_max term alone), f(0)=0. 16 iters -> |dtau|<=1.5e-5,
        // output err <= ~3e-5 << 1.1e-2 threshold.
        float lo = -1.0f, hi = 0.0f;
        for (int it = 0; it < 16; ++it) {
            const float tau = 0.5f * (lo + hi);
            float f0 = 0.0f, f1 = 0.0f, f2 = 0.0f, f3 = 0.0f;
#pragma unroll
            for (int r = 0; r < 8; ++r) {
                float a0 = fmaxf(sc[p][4 * r + 0] - tau, 0.0f);
                float a1 = fmaxf(sc[p][4 * r + 1] - tau, 0.0f);
                float a2 = fmaxf(sc[p][4 * r + 2] - tau, 0.0f);
                float a3 = fmaxf(sc[p][4 * r + 3] - tau, 0.0f);
                f0 = fmaf(a0, a0, f0);
                f1 = fmaf(a1, a1, f1);
                f2 = fmaf(a2, a2, f2);
                f3 = fmaf(a3, a3, f3);
            }
            float fs = (f0 + f1) + (f2 + f3);
#pragma unroll
            for (int off = 32; off >= 1; off >>= 1) fs += __shfl_xor(fs, off);
            if (fs >= 1.0f) lo = tau; else hi = tau;
        }
        const float tau = 0.5f * (lo + hi);

        // p_j = max(z_j - tau, 0)^2 -> f32, two float4 (32B) per lane per group
        float* orow = out + (size_t)(row0 + p) * SEQ;
#pragma unroll
        for (int g = 0; g < 4; ++g) {
            float pv[8];
#pragma unroll
            for (int u = 0; u < 8; ++u) {
                float dz = fmaxf(sc[p][g * 8 + u] - tau, 0.0f);
                pv[u] = dz * dz;
            }
            float4 lov = make_float4(pv[0], pv[1], pv[2], pv[3]);
            float4 hiv = make_float4(pv[4], pv[5], pv[6], pv[7]);
            *reinterpret_cast<float4*>(orow + g * 512 + t * 8)     = lov;
            *reinterpret_cast<float4*>(orow + g * 512 + t * 8 + 4) = hiv;
        }
    }
}

// ---------------------------------------------------------------------------
extern "C" void kernel_launch(void* const* d_in, const int* in_sizes, int n_in,
                              void* d_out, int out_size, void* d_ws, size_t ws_size,
                              hipStream_t stream) {
    const float* x_c = (const float*)d_in[0];
    const float* x_n = (const float*)d_in[1];
    const float* Wq  = (const float*)d_in[2];
    const float* bq  = (const float*)d_in[3];
    const float* Wk  = (const float*)d_in[4];
    const float* bk  = (const float*)d_in[5];
    float* out = (float*)d_out;

    char* ws = (char*)d_ws;
    float*          Qf   = (float*)ws;                                       // 8 MB
    __hip_bfloat16* Krow = (__hip_bfloat16*)(ws + (size_t)8  * 1024 * 1024); // 4 MB
    __hip_bfloat16* Kt   = (__hip_bfloat16*)(ws + (size_t)12 * 1024 * 1024); // 4 MB

    project_f32 <<<BATCH * SEQ / 8, 128, 0, stream>>>(x_c, Wq, bq, Qf);
    project_bf16<<<BATCH * SEQ / 8, 128, 0, stream>>>(x_n, Wk, bk, Krow);
    transpose_k <<<dim3(SEQ / 64, DIM / 64, BATCH), 256, 0, stream>>>(Krow, Kt);
    attn_entmax_kernel<<<BATCH * SEQ / 4, 64, 0, stream>>>(Qf, Kt, out);
}